// Round 3
// baseline (281.884 us; speedup 1.0000x reference)
//
#include <hip/hip_runtime.h>
#include <stdint.h>

// Problem constants: B=4, C=256, H=W=64 -> N=4096, HEADS=4, DH=64, GROUPS=8
#define NB    4
#define CC    256
#define NN    4096
#define NHEAD 4
#define DH    64
#define NGRP  8
#define GSIZE 131072   // (CC/NGRP)*NN elements per (b,group)

typedef unsigned short u16;
typedef __attribute__((ext_vector_type(8))) short s16x8;   // 8 bf16 in 4 VGPRs
typedef __attribute__((ext_vector_type(4))) float f32x4;

__device__ __forceinline__ u16 f2b(float f) {
  uint32_t x = __float_as_uint(f);
  x += 0x7fffu + ((x >> 16) & 1u);   // RNE
  return (u16)(x >> 16);
}

// ---------------- prep: zero stats + fp32->bf16 weights ----------------
__global__ __launch_bounds__(256) void k_prep(const float* __restrict__ qw,
                                              const float* __restrict__ pw,
                                              u16* __restrict__ qwb,
                                              u16* __restrict__ pwb,
                                              float* __restrict__ stats) {
  int i = blockIdx.x * 256 + threadIdx.x;
  if (i < 64) stats[i] = 0.f;
  for (int idx = i; idx < 3 * CC * CC; idx += 65536) qwb[idx] = f2b(qw[idx]);
  if (i < CC * CC) pwb[i] = f2b(pw[i]);
}

// ---------------- groupnorm stats: sum/sumsq per (b,g) -----------------
__global__ __launch_bounds__(256) void k_gn_stats(const float* __restrict__ x,
                                                  float* __restrict__ stats) {
  int grp = blockIdx.x >> 4, sub = blockIdx.x & 15;
  const float4* p4 = (const float4*)(x + (size_t)grp * GSIZE + (size_t)sub * 8192);
  float s = 0.f, s2 = 0.f;
#pragma unroll
  for (int i = 0; i < 8; ++i) {
    float4 v = p4[threadIdx.x + 256 * i];
    s  += v.x + v.y + v.z + v.w;
    s2 += v.x * v.x + v.y * v.y + v.z * v.z + v.w * v.w;
  }
#pragma unroll
  for (int off = 1; off < 64; off <<= 1) { s += __shfl_xor(s, off); s2 += __shfl_xor(s2, off); }
  __shared__ float red[8];
  int w = threadIdx.x >> 6;
  if ((threadIdx.x & 63) == 0) { red[w] = s; red[4 + w] = s2; }
  __syncthreads();
  if (threadIdx.x == 0) {
    s  = red[0] + red[1] + red[2] + red[3];
    s2 = red[4] + red[5] + red[6] + red[7];
    atomicAdd(&stats[grp], s);
    atomicAdd(&stats[32 + grp], s2);
  }
}

// ------------- groupnorm normalize + transpose to h_t[b][n][c] ---------
__global__ __launch_bounds__(256) void k_gn_norm(const float* __restrict__ x,
                                                 const float* __restrict__ stats,
                                                 const float* __restrict__ gw,
                                                 const float* __restrict__ gb,
                                                 u16* __restrict__ ht) {
  __shared__ u16 T[64 * 72];
  int b = blockIdx.z, cb = blockIdx.y, nb = blockIdx.x;
  int t = threadIdx.x;
  int c = t >> 2, nch = (t & 3) * 16;
  int cg = cb * 64 + c;
  int grp = b * NGRP + (cg >> 5);
  float mean = stats[grp] * (1.f / (float)GSIZE);
  float var  = stats[32 + grp] * (1.f / (float)GSIZE) - mean * mean;
  float rstd = rsqrtf(var + 1e-5f);
  float ga = gw[cg] * rstd;
  float be = gb[cg] - mean * ga;
  const float* px = x + ((size_t)b * CC + cg) * NN + nb * 64 + nch;
#pragma unroll
  for (int k = 0; k < 4; ++k) {
    float4 v = *(const float4*)(px + 4 * k);
    int nl = nch + 4 * k;
    T[(nl + 0) * 72 + c] = f2b(v.x * ga + be);
    T[(nl + 1) * 72 + c] = f2b(v.y * ga + be);
    T[(nl + 2) * 72 + c] = f2b(v.z * ga + be);
    T[(nl + 3) * 72 + c] = f2b(v.w * ga + be);
  }
  __syncthreads();
  int n = t >> 2, cch = (t & 3) * 16;
  u16* dst = ht + ((size_t)b * NN + nb * 64 + n) * CC + cb * 64 + cch;
  *(uint4*)(dst)     = *(const uint4*)&T[n * 72 + cch];
  *(uint4*)(dst + 8) = *(const uint4*)&T[n * 72 + cch + 8];
}

// ---------------- QKV GEMM: C[o][n] = qkv_w[o][:] . h[:, n] ------------
__global__ __launch_bounds__(256) void k_qkv(const u16* __restrict__ Aw,
                                             const float* __restrict__ bias,
                                             const u16* __restrict__ ht,
                                             u16* __restrict__ Qt,
                                             u16* __restrict__ Kt,
                                             u16* __restrict__ Vv) {
  __shared__ u16 sm[5120];            // As[64][40] | Bs[64][40]; reused as Ts[64][72]
  u16* As = sm;
  u16* Bs = sm + 2560;
  int b = blockIdx.z, bm = blockIdx.y, bn = blockIdx.x;
  int t = threadIdx.x, w = t >> 6, lane = t & 63, lr = lane & 15, lg = lane >> 4;
  int wm = w >> 1, wn = w & 1;
  int srow = t >> 2, sch = (t & 3) * 8;
  const u16* Ap = Aw + (size_t)(bm * 64 + srow) * CC + sch;
  const u16* Bp = ht + ((size_t)b * NN + bn * 64 + srow) * CC + sch;
  f32x4 acc[2][2] = {};
  for (int kt = 0; kt < CC / 32; ++kt) {
    *(uint4*)&As[srow * 40 + sch] = *(const uint4*)(Ap + kt * 32);
    *(uint4*)&Bs[srow * 40 + sch] = *(const uint4*)(Bp + kt * 32);
    __syncthreads();
    s16x8 af[2], bf[2];
#pragma unroll
    for (int fm = 0; fm < 2; ++fm) af[fm] = *(const s16x8*)&As[(wm * 32 + fm * 16 + lr) * 40 + lg * 8];
#pragma unroll
    for (int fn = 0; fn < 2; ++fn) bf[fn] = *(const s16x8*)&Bs[(wn * 32 + fn * 16 + lr) * 40 + lg * 8];
#pragma unroll
    for (int fm = 0; fm < 2; ++fm)
#pragma unroll
      for (int fn = 0; fn < 2; ++fn)
        acc[fm][fn] = __builtin_amdgcn_mfma_f32_16x16x32_bf16(af[fm], bf[fn], acc[fm][fn], 0, 0, 0);
    __syncthreads();
  }
  int which = bm >> 2, head = bm & 3;
  if (which == 2) {           // V[b][h][d][n], d = local row m
#pragma unroll
    for (int fm = 0; fm < 2; ++fm)
#pragma unroll
      for (int fn = 0; fn < 2; ++fn)
#pragma unroll
        for (int r = 0; r < 4; ++r) {
          int m = wm * 32 + fm * 16 + lg * 4 + r;
          int n = wn * 32 + fn * 16 + lr;
          float v = acc[fm][fn][r] + bias[bm * 64 + m];
          Vv[((size_t)(b * NHEAD + head) * DH + m) * NN + bn * 64 + n] = f2b(v);
        }
  } else {                    // Qt/Kt[b][h][n][d] via LDS transpose
    u16* Ts = sm;             // [64 n][72]
    float scale = (which == 0) ? 0.125f : 1.0f;
#pragma unroll
    for (int fm = 0; fm < 2; ++fm)
#pragma unroll
      for (int fn = 0; fn < 2; ++fn)
#pragma unroll
        for (int r = 0; r < 4; ++r) {
          int m = wm * 32 + fm * 16 + lg * 4 + r;
          int n = wn * 32 + fn * 16 + lr;
          float v = (acc[fm][fn][r] + bias[bm * 64 + m]) * scale;
          Ts[n * 72 + m] = f2b(v);
        }
    __syncthreads();
    u16* dst = (which == 0 ? Qt : Kt);
    int n = t >> 2, cch = (t & 3) * 16;
    u16* o = dst + ((size_t)(b * NHEAD + head) * NN + bn * 64 + n) * DH + cch;
    *(uint4*)(o)     = *(const uint4*)&Ts[n * 72 + cch];
    *(uint4*)(o + 8) = *(const uint4*)&Ts[n * 72 + cch + 8];
  }
}

// ---------------- flash attention --------------------------------------
// grid (qtile=N/64, b*h). 4 waves x 16 q-rows. KV tile = 64, staged in LDS.
__global__ __launch_bounds__(256) void k_attn(const u16* __restrict__ Qt,
                                              const u16* __restrict__ Kt,
                                              const u16* __restrict__ Vv,
                                              u16* __restrict__ att) {
  __shared__ u16 Ks[64 * 72];       // [j][d]  (rows of Kt)
  __shared__ u16 Vs[64 * 72];       // [d][j]  (rows of V)
  __shared__ u16 Ps[4 * 16 * 72];   // per-wave P [i][j]
  int bh = blockIdx.y, qt = blockIdx.x;
  int t = threadIdx.x, w = t >> 6, lane = t & 63, lr = lane & 15, lg = lane >> 4;
  const u16* Qb = Qt + ((size_t)bh * NN + qt * 64 + w * 16) * DH;
  const u16* Kb = Kt + (size_t)bh * NN * DH;
  const u16* Vb = Vv + (size_t)bh * DH * NN;
  // Q fragments (A-layout: row=lr, k=lg*8+j), already scaled by 1/8
  s16x8 aq[2];
#pragma unroll
  for (int kk = 0; kk < 2; ++kk) aq[kk] = *(const s16x8*)(Qb + lr * DH + kk * 32 + lg * 8);
  float m_r[4], l_r[4];
  f32x4 oacc[4] = {};
#pragma unroll
  for (int r = 0; r < 4; ++r) { m_r[r] = -1e30f; l_r[r] = 0.f; }
  u16* Pw = Ps + w * 16 * 72;
  // staging: full 64x64 tile = 4096 u16; 256 thr x 16 u16 (two uint4 each)
  int srow = t >> 2, sch = (t & 3) * 16;
  for (int j0 = 0; j0 < NN; j0 += 64) {
    const u16* kp = Kb + (size_t)(j0 + srow) * DH + sch;
    const u16* vp = Vb + (size_t)srow * NN + j0 + sch;
    *(uint4*)&Ks[srow * 72 + sch]     = *(const uint4*)(kp);
    *(uint4*)&Ks[srow * 72 + sch + 8] = *(const uint4*)(kp + 8);
    *(uint4*)&Vs[srow * 72 + sch]     = *(const uint4*)(vp);
    *(uint4*)&Vs[srow * 72 + sch + 8] = *(const uint4*)(vp + 8);
    __syncthreads();
    // S = Q K^T : D[i=lg*4+r][j=jt*16+lr]
    f32x4 s[4];
#pragma unroll
    for (int jt = 0; jt < 4; ++jt) {
      f32x4 z = {};
      s16x8 bk0 = *(const s16x8*)&Ks[(jt * 16 + lr) * 72 + lg * 8];
      s16x8 bk1 = *(const s16x8*)&Ks[(jt * 16 + lr) * 72 + 32 + lg * 8];
      z = __builtin_amdgcn_mfma_f32_16x16x32_bf16(aq[0], bk0, z, 0, 0, 0);
      z = __builtin_amdgcn_mfma_f32_16x16x32_bf16(aq[1], bk1, z, 0, 0, 0);
      s[jt] = z;
    }
    // online softmax per accumulator register r (row i = lg*4 + r)
#pragma unroll
    for (int r = 0; r < 4; ++r) {
      float mx = fmaxf(fmaxf(s[0][r], s[1][r]), fmaxf(s[2][r], s[3][r]));
      mx = fmaxf(mx, __shfl_xor(mx, 1));
      mx = fmaxf(mx, __shfl_xor(mx, 2));
      mx = fmaxf(mx, __shfl_xor(mx, 4));
      mx = fmaxf(mx, __shfl_xor(mx, 8));
      float mnew  = fmaxf(m_r[r], mx);
      float alpha = __expf(m_r[r] - mnew);
      float rs = 0.f;
#pragma unroll
      for (int jt = 0; jt < 4; ++jt) {
        float pv = __expf(s[jt][r] - mnew);
        rs += pv;
        Pw[(lg * 4 + r) * 72 + jt * 16 + lr] = f2b(pv);
      }
      rs += __shfl_xor(rs, 1);
      rs += __shfl_xor(rs, 2);
      rs += __shfl_xor(rs, 4);
      rs += __shfl_xor(rs, 8);
      l_r[r] = l_r[r] * alpha + rs;
      m_r[r] = mnew;
#pragma unroll
      for (int dt = 0; dt < 4; ++dt) oacc[dt][r] *= alpha;
    }
    __asm__ volatile("s_waitcnt lgkmcnt(0)" ::: "memory");  // P writes visible to own wave
    __builtin_amdgcn_sched_barrier(0);
    // O += P V^T : A = P[i][j] (row=lr), B[k=j][col=d] from Vs[d][j]
#pragma unroll
    for (int js = 0; js < 2; ++js) {
      s16x8 pa = *(const s16x8*)&Pw[lr * 72 + js * 32 + lg * 8];
#pragma unroll
      for (int dt = 0; dt < 4; ++dt) {
        s16x8 bv = *(const s16x8*)&Vs[(dt * 16 + lr) * 72 + js * 32 + lg * 8];
        oacc[dt] = __builtin_amdgcn_mfma_f32_16x16x32_bf16(pa, bv, oacc[dt], 0, 0, 0);
      }
    }
    __syncthreads();
  }
  // write att_t[b][n][c], c = h*64 + dt*16 + lr, n = qt*64 + w*16 + lg*4 + r
  int b = bh >> 2, h = bh & 3;
#pragma unroll
  for (int dt = 0; dt < 4; ++dt)
#pragma unroll
    for (int r = 0; r < 4; ++r) {
      int n = qt * 64 + w * 16 + lg * 4 + r;
      int c = h * 64 + dt * 16 + lr;
      att[((size_t)b * NN + n) * CC + c] = f2b(oacc[dt][r] / l_r[r]);
    }
}

// ---------------- proj GEMM + residual ---------------------------------
__global__ __launch_bounds__(256) void k_proj(const u16* __restrict__ Aw,
                                              const float* __restrict__ bias,
                                              const u16* __restrict__ att,
                                              const float* __restrict__ x,
                                              float* __restrict__ out) {
  __shared__ u16 sm[5120];
  u16* As = sm;
  u16* Bs = sm + 2560;
  int b = blockIdx.z, bm = blockIdx.y, bn = blockIdx.x;
  int t = threadIdx.x, w = t >> 6, lane = t & 63, lr = lane & 15, lg = lane >> 4;
  int wm = w >> 1, wn = w & 1;
  int srow = t >> 2, sch = (t & 3) * 8;
  const u16* Ap = Aw + (size_t)(bm * 64 + srow) * CC + sch;
  const u16* Bp = att + ((size_t)b * NN + bn * 64 + srow) * CC + sch;
  f32x4 acc[2][2] = {};
  for (int kt = 0; kt < CC / 32; ++kt) {
    *(uint4*)&As[srow * 40 + sch] = *(const uint4*)(Ap + kt * 32);
    *(uint4*)&Bs[srow * 40 + sch] = *(const uint4*)(Bp + kt * 32);
    __syncthreads();
    s16x8 af[2], bf[2];
#pragma unroll
    for (int fm = 0; fm < 2; ++fm) af[fm] = *(const s16x8*)&As[(wm * 32 + fm * 16 + lr) * 40 + lg * 8];
#pragma unroll
    for (int fn = 0; fn < 2; ++fn) bf[fn] = *(const s16x8*)&Bs[(wn * 32 + fn * 16 + lr) * 40 + lg * 8];
#pragma unroll
    for (int fm = 0; fm < 2; ++fm)
#pragma unroll
      for (int fn = 0; fn < 2; ++fn)
        acc[fm][fn] = __builtin_amdgcn_mfma_f32_16x16x32_bf16(af[fm], bf[fn], acc[fm][fn], 0, 0, 0);
    __syncthreads();
  }
#pragma unroll
  for (int fm = 0; fm < 2; ++fm)
#pragma unroll
    for (int fn = 0; fn < 2; ++fn)
#pragma unroll
      for (int r = 0; r < 4; ++r) {
        int o = bm * 64 + wm * 32 + fm * 16 + lg * 4 + r;
        int n = bn * 64 + wn * 32 + fn * 16 + lr;
        size_t idx = ((size_t)b * CC + o) * NN + n;
        out[idx] = x[idx] + bias[o] + acc[fm][fn][r];
      }
}

// ---------------- launch ------------------------------------------------
extern "C" void kernel_launch(void* const* d_in, const int* in_sizes, int n_in,
                              void* d_out, int out_size, void* d_ws, size_t ws_size,
                              hipStream_t stream) {
  const float* x  = (const float*)d_in[0];
  const float* nw = (const float*)d_in[1];
  const float* nb = (const float*)d_in[2];
  const float* qw = (const float*)d_in[3];
  const float* qb = (const float*)d_in[4];
  const float* pw = (const float*)d_in[5];
  const float* pb = (const float*)d_in[6];
  float* out = (float*)d_out;
  char* ws = (char*)d_ws;
  float* stats = (float*)(ws + 0);            // 64 f32
  u16* qwb = (u16*)(ws + 4096);               // 768*256 bf16
  u16* pwb = (u16*)(ws + 397312);             // 256*256 bf16
  u16* ht  = (u16*)(ws + 528384);             // [B][N][C] bf16  (8 MB)
  u16* Qt  = (u16*)(ws + 8916992);            // [B][H][N][D] bf16
  u16* Kt  = (u16*)(ws + 17305600);           // [B][H][N][D] bf16
  u16* Vv  = (u16*)(ws + 25694208);           // [B][H][D][N] bf16
  u16* att = (u16*)(ws + 34082816);           // [B][N][C] bf16

  k_prep<<<dim3(256), dim3(256), 0, stream>>>(qw, pw, qwb, pwb, stats);
  k_gn_stats<<<dim3(512), dim3(256), 0, stream>>>(x, stats);
  k_gn_norm<<<dim3(64, 4, NB), dim3(256), 0, stream>>>(x, stats, nw, nb, ht);
  k_qkv<<<dim3(64, 12, NB), dim3(256), 0, stream>>>(qwb, qb, ht, Qt, Kt, Vv);
  k_attn<<<dim3(64, NB * NHEAD), dim3(256), 0, stream>>>(Qt, Kt, Vv, att);
  k_proj<<<dim3(64, 4, NB), dim3(256), 0, stream>>>(pwb, pb, att, x, out);
}

// Round 4
// 177.773 us; speedup vs baseline: 1.5856x; 1.5856x over previous
//
#include <hip/hip_runtime.h>
#include <stdint.h>

// Problem constants: B=4, C=256, H=W=64 -> N=4096, HEADS=4, DH=64, GROUPS=8
#define NB    4
#define CC    256
#define NN    4096
#define NHEAD 4
#define DH    64
#define NGRP  8
#define GSIZE 131072   // (CC/NGRP)*NN elements per (b,group)

typedef unsigned short u16;
typedef __attribute__((ext_vector_type(8))) short s16x8;   // 8 bf16 in 4 VGPRs
typedef __attribute__((ext_vector_type(4))) float f32x4;

__device__ __forceinline__ u16 f2b(float f) {
  uint32_t x = __float_as_uint(f);
  x += 0x7fffu + ((x >> 16) & 1u);   // RNE
  return (u16)(x >> 16);
}

__device__ __forceinline__ uint32_t pk2(float a, float b) {
  uint32_t r;
  asm("v_cvt_pk_bf16_f32 %0, %1, %2" : "=v"(r) : "v"(a), "v"(b));
  return r;   // a -> [15:0], b -> [31:16]
}

// ---------------- prep: zero stats + fp32->bf16 weights ----------------
__global__ __launch_bounds__(256) void k_prep(const float* __restrict__ qw,
                                              const float* __restrict__ pw,
                                              u16* __restrict__ qwb,
                                              u16* __restrict__ pwb,
                                              float* __restrict__ stats) {
  int i = blockIdx.x * 256 + threadIdx.x;
  if (i < 64) stats[i] = 0.f;
  for (int idx = i; idx < 3 * CC * CC; idx += 65536) qwb[idx] = f2b(qw[idx]);
  if (i < CC * CC) pwb[i] = f2b(pw[i]);
}

// ---------------- groupnorm stats: sum/sumsq per (b,g) -----------------
__global__ __launch_bounds__(256) void k_gn_stats(const float* __restrict__ x,
                                                  float* __restrict__ stats) {
  int grp = blockIdx.x >> 4, sub = blockIdx.x & 15;
  const float4* p4 = (const float4*)(x + (size_t)grp * GSIZE + (size_t)sub * 8192);
  float s = 0.f, s2 = 0.f;
#pragma unroll
  for (int i = 0; i < 8; ++i) {
    float4 v = p4[threadIdx.x + 256 * i];
    s  += v.x + v.y + v.z + v.w;
    s2 += v.x * v.x + v.y * v.y + v.z * v.z + v.w * v.w;
  }
#pragma unroll
  for (int off = 1; off < 64; off <<= 1) { s += __shfl_xor(s, off); s2 += __shfl_xor(s2, off); }
  __shared__ float red[8];
  int w = threadIdx.x >> 6;
  if ((threadIdx.x & 63) == 0) { red[w] = s; red[4 + w] = s2; }
  __syncthreads();
  if (threadIdx.x == 0) {
    s  = red[0] + red[1] + red[2] + red[3];
    s2 = red[4] + red[5] + red[6] + red[7];
    atomicAdd(&stats[grp], s);
    atomicAdd(&stats[32 + grp], s2);
  }
}

// ------------- groupnorm normalize + transpose to h_t[b][n][c] ---------
__global__ __launch_bounds__(256) void k_gn_norm(const float* __restrict__ x,
                                                 const float* __restrict__ stats,
                                                 const float* __restrict__ gw,
                                                 const float* __restrict__ gb,
                                                 u16* __restrict__ ht) {
  __shared__ u16 T[64 * 72];
  int b = blockIdx.z, cb = blockIdx.y, nb = blockIdx.x;
  int t = threadIdx.x;
  int c = t >> 2, nch = (t & 3) * 16;
  int cg = cb * 64 + c;
  int grp = b * NGRP + (cg >> 5);
  float mean = stats[grp] * (1.f / (float)GSIZE);
  float var  = stats[32 + grp] * (1.f / (float)GSIZE) - mean * mean;
  float rstd = rsqrtf(var + 1e-5f);
  float ga = gw[cg] * rstd;
  float be = gb[cg] - mean * ga;
  const float* px = x + ((size_t)b * CC + cg) * NN + nb * 64 + nch;
#pragma unroll
  for (int k = 0; k < 4; ++k) {
    float4 v = *(const float4*)(px + 4 * k);
    int nl = nch + 4 * k;
    T[(nl + 0) * 72 + c] = f2b(v.x * ga + be);
    T[(nl + 1) * 72 + c] = f2b(v.y * ga + be);
    T[(nl + 2) * 72 + c] = f2b(v.z * ga + be);
    T[(nl + 3) * 72 + c] = f2b(v.w * ga + be);
  }
  __syncthreads();
  int n = t >> 2, cch = (t & 3) * 16;
  u16* dst = ht + ((size_t)b * NN + nb * 64 + n) * CC + cb * 64 + cch;
  *(uint4*)(dst)     = *(const uint4*)&T[n * 72 + cch];
  *(uint4*)(dst + 8) = *(const uint4*)&T[n * 72 + cch + 8];
}

// ---------------- QKV GEMM: C[o][n] = qkv_w[o][:] . h[:, n] ------------
__global__ __launch_bounds__(256) void k_qkv(const u16* __restrict__ Aw,
                                             const float* __restrict__ bias,
                                             const u16* __restrict__ ht,
                                             u16* __restrict__ Qt,
                                             u16* __restrict__ Kt,
                                             u16* __restrict__ Vv) {
  __shared__ u16 sm[5120];            // As[64][40] | Bs[64][40]; reused as Ts[64][72]
  u16* As = sm;
  u16* Bs = sm + 2560;
  int b = blockIdx.z, bm = blockIdx.y, bn = blockIdx.x;
  int t = threadIdx.x, w = t >> 6, lane = t & 63, lr = lane & 15, lg = lane >> 4;
  int wm = w >> 1, wn = w & 1;
  int srow = t >> 2, sch = (t & 3) * 8;
  const u16* Ap = Aw + (size_t)(bm * 64 + srow) * CC + sch;
  const u16* Bp = ht + ((size_t)b * NN + bn * 64 + srow) * CC + sch;
  f32x4 acc[2][2] = {};
  for (int kt = 0; kt < CC / 32; ++kt) {
    *(uint4*)&As[srow * 40 + sch] = *(const uint4*)(Ap + kt * 32);
    *(uint4*)&Bs[srow * 40 + sch] = *(const uint4*)(Bp + kt * 32);
    __syncthreads();
    s16x8 af[2], bf[2];
#pragma unroll
    for (int fm = 0; fm < 2; ++fm) af[fm] = *(const s16x8*)&As[(wm * 32 + fm * 16 + lr) * 40 + lg * 8];
#pragma unroll
    for (int fn = 0; fn < 2; ++fn) bf[fn] = *(const s16x8*)&Bs[(wn * 32 + fn * 16 + lr) * 40 + lg * 8];
#pragma unroll
    for (int fm = 0; fm < 2; ++fm)
#pragma unroll
      for (int fn = 0; fn < 2; ++fn)
        acc[fm][fn] = __builtin_amdgcn_mfma_f32_16x16x32_bf16(af[fm], bf[fn], acc[fm][fn], 0, 0, 0);
    __syncthreads();
  }
  int which = bm >> 2, head = bm & 3;
  if (which == 2) {           // V[b][h][d][n], d = local row m
#pragma unroll
    for (int fm = 0; fm < 2; ++fm)
#pragma unroll
      for (int fn = 0; fn < 2; ++fn)
#pragma unroll
        for (int r = 0; r < 4; ++r) {
          int m = wm * 32 + fm * 16 + lg * 4 + r;
          int n = wn * 32 + fn * 16 + lr;
          float v = acc[fm][fn][r] + bias[bm * 64 + m];
          Vv[((size_t)(b * NHEAD + head) * DH + m) * NN + bn * 64 + n] = f2b(v);
        }
  } else {                    // Qt/Kt[b][h][n][d] via LDS transpose
    u16* Ts = sm;             // [64 n][72]
    // Q carries 1/sqrt(d) * log2(e) so attention scores are in exp2 domain
    float scale = (which == 0) ? 0.125f * 1.44269504f : 1.0f;
#pragma unroll
    for (int fm = 0; fm < 2; ++fm)
#pragma unroll
      for (int fn = 0; fn < 2; ++fn)
#pragma unroll
        for (int r = 0; r < 4; ++r) {
          int m = wm * 32 + fm * 16 + lg * 4 + r;
          int n = wn * 32 + fn * 16 + lr;
          float v = (acc[fm][fn][r] + bias[bm * 64 + m]) * scale;
          Ts[n * 72 + m] = f2b(v);
        }
    __syncthreads();
    u16* dst = (which == 0 ? Qt : Kt);
    int n = t >> 2, cch = (t & 3) * 16;
    u16* o = dst + ((size_t)(b * NHEAD + head) * NN + bn * 64 + n) * DH + cch;
    *(uint4*)(o)     = *(const uint4*)&Ts[n * 72 + cch];
    *(uint4*)(o + 8) = *(const uint4*)&Ts[n * 72 + cch + 8];
  }
}

// ---------------- flash attention (swapped-operand, in-register P) -----
// grid (qtile=N/64, b*h). 4 waves x 16 q-rows each. KVBLK=64.
// S^T = K.Q^T via mfma(A=Kfrag,B=Qfrag): lane owns q-row i=lane&15,
// 16 S-values j* = jt1*32 + lg*8 + jt0*4 + r (K rows staged permuted so
// the accumulator layout IS the PV B-fragment layout -> repack = 8 cvt_pk).
// PV: O^T = V^T.P^T, D col = i = lane&15 (same row as softmax scalars).
__global__ __launch_bounds__(256, 4) void k_attn(const u16* __restrict__ Qt,
                                                 const u16* __restrict__ Kt,
                                                 const u16* __restrict__ Vv,
                                                 u16* __restrict__ att) {
  __shared__ __align__(16) u16 Ks[64 * 72];   // [rho][d], row rho holds K[j0+pi(rho)]
  __shared__ __align__(16) u16 Vs[64 * 72];   // [d][j], natural j order
  int bh = blockIdx.y, qt = blockIdx.x;
  int t = threadIdx.x, w = t >> 6, lane = t & 63, lr = lane & 15, lg = lane >> 4;
  const u16* Qb = Qt + ((size_t)bh * NN + qt * 64 + w * 16) * DH;
  const u16* Kb = Kt + (size_t)bh * NN * DH;
  const u16* Vb = Vv + (size_t)bh * DH * NN;
  // Q B-frag: B[k=d][col=i=lr] = Qt[qbase+lr][d=kk*32+lg*8+idx]
  s16x8 bq[2];
#pragma unroll
  for (int kk = 0; kk < 2; ++kk) bq[kk] = *(const s16x8*)(Qb + lr * DH + kk * 32 + lg * 8);
  float m = -1e30f, l = 0.f;
  f32x4 oacc[4] = {};
  // staging: thread srow covers LDS row srow, 16 cols at sch
  int srow = t >> 2, sch = (t & 3) * 16;
  // pi: rho bits [jt1 jt0 lg1 lg0 r1 r0] -> j bits [jt1 lg1 lg0 jt0 r1 r0]
  int prow = (srow & 32) | (((srow >> 2) & 3) << 3) | (((srow >> 4) & 1) << 2) | (srow & 3);
  const u16* kp0 = Kb + (size_t)prow * DH + sch;
  const u16* vp0 = Vb + (size_t)srow * NN + sch;
  // prologue: stage tile 0
  uint4 rk0 = *(const uint4*)(kp0), rk1 = *(const uint4*)(kp0 + 8);
  uint4 rv0 = *(const uint4*)(vp0), rv1 = *(const uint4*)(vp0 + 8);
  *(uint4*)&Ks[srow * 72 + sch]     = rk0;
  *(uint4*)&Ks[srow * 72 + sch + 8] = rk1;
  *(uint4*)&Vs[srow * 72 + sch]     = rv0;
  *(uint4*)&Vs[srow * 72 + sch + 8] = rv1;
  __syncthreads();
  for (int j0 = 0; j0 < NN; j0 += 64) {
    // prefetch next K/V tile into registers (T14: hide HBM under compute)
    int jn = (j0 + 64 < NN) ? j0 + 64 : 0;
    const u16* kp = kp0 + (size_t)jn * DH;
    const u16* vp = vp0 + jn;
    rk0 = *(const uint4*)(kp);  rk1 = *(const uint4*)(kp + 8);
    rv0 = *(const uint4*)(vp);  rv1 = *(const uint4*)(vp + 8);
    // S^T: 4 jt tiles, K=64 in 2 chunks
    f32x4 s[4];
#pragma unroll
    for (int jt = 0; jt < 4; ++jt) {
      f32x4 z = {};
      s16x8 a0 = *(const s16x8*)&Ks[(jt * 16 + lr) * 72 + lg * 8];
      s16x8 a1 = *(const s16x8*)&Ks[(jt * 16 + lr) * 72 + 32 + lg * 8];
      z = __builtin_amdgcn_mfma_f32_16x16x32_bf16(a0, bq[0], z, 0, 0, 0);
      z = __builtin_amdgcn_mfma_f32_16x16x32_bf16(a1, bq[1], z, 0, 0, 0);
      s[jt] = z;
    }
    // row max (lane owns row i=lr; lg groups hold disjoint j)
    float mx = s[0][0];
#pragma unroll
    for (int jt = 0; jt < 4; ++jt)
#pragma unroll
      for (int r = 0; r < 4; ++r) mx = fmaxf(mx, s[jt][r]);
    mx = fmaxf(mx, __shfl_xor(mx, 16));
    mx = fmaxf(mx, __shfl_xor(mx, 32));
    // defer-max: rescale only if some row grew by > 8 (exp2 domain)
    if (__any(mx > m + 8.f)) {
      float mnew  = fmaxf(m, mx);
      float alpha = exp2f(m - mnew);
      l *= alpha;
#pragma unroll
      for (int dt = 0; dt < 4; ++dt)
#pragma unroll
        for (int r = 0; r < 4; ++r) oacc[dt][r] *= alpha;
      m = mnew;
    }
    float p[4][4];
    float rs = 0.f;
#pragma unroll
    for (int jt = 0; jt < 4; ++jt)
#pragma unroll
      for (int r = 0; r < 4; ++r) {
        float pv = exp2f(s[jt][r] - m);
        p[jt][r] = pv;
        rs += pv;
      }
    rs += __shfl_xor(rs, 16);
    rs += __shfl_xor(rs, 32);
    l += rs;
    // pack P into PV B-frags (pure in-lane, thanks to pi-permuted K rows)
    union { s16x8 v; uint32_t u[4]; } pb0, pb1;
    pb0.u[0] = pk2(p[0][0], p[0][1]); pb0.u[1] = pk2(p[0][2], p[0][3]);
    pb0.u[2] = pk2(p[1][0], p[1][1]); pb0.u[3] = pk2(p[1][2], p[1][3]);
    pb1.u[0] = pk2(p[2][0], p[2][1]); pb1.u[1] = pk2(p[2][2], p[2][3]);
    pb1.u[2] = pk2(p[3][0], p[3][1]); pb1.u[3] = pk2(p[3][2], p[3][3]);
    // O^T += V^T . P^T : A[row=d=dt*16+lr][k=j], B[k=j][col=i=lr]
#pragma unroll
    for (int dt = 0; dt < 4; ++dt) {
      s16x8 av0 = *(const s16x8*)&Vs[(dt * 16 + lr) * 72 + lg * 8];
      s16x8 av1 = *(const s16x8*)&Vs[(dt * 16 + lr) * 72 + 32 + lg * 8];
      oacc[dt] = __builtin_amdgcn_mfma_f32_16x16x32_bf16(av0, pb0.v, oacc[dt], 0, 0, 0);
      oacc[dt] = __builtin_amdgcn_mfma_f32_16x16x32_bf16(av1, pb1.v, oacc[dt], 0, 0, 0);
    }
    __syncthreads();   // all waves done reading Ks/Vs
    *(uint4*)&Ks[srow * 72 + sch]     = rk0;
    *(uint4*)&Ks[srow * 72 + sch + 8] = rk1;
    *(uint4*)&Vs[srow * 72 + sch]     = rv0;
    *(uint4*)&Vs[srow * 72 + sch + 8] = rv1;
    __syncthreads();   // next tile staged
  }
  // write att[b][n][c]: n = qt*64+w*16+lr, c = h*64 + dt*16 + lg*4 + r
  float linv = 1.f / l;
  int b = bh >> 2, h = bh & 3;
  u16* ob = att + ((size_t)b * NN + qt * 64 + w * 16 + lr) * CC + h * 64 + lg * 4;
#pragma unroll
  for (int dt = 0; dt < 4; ++dt) {
    uint2 pkd;
    pkd.x = pk2(oacc[dt][0] * linv, oacc[dt][1] * linv);
    pkd.y = pk2(oacc[dt][2] * linv, oacc[dt][3] * linv);
    *(uint2*)(ob + dt * 16) = pkd;
  }
}

// ---------------- proj GEMM + residual ---------------------------------
__global__ __launch_bounds__(256) void k_proj(const u16* __restrict__ Aw,
                                              const float* __restrict__ bias,
                                              const u16* __restrict__ att,
                                              const float* __restrict__ x,
                                              float* __restrict__ out) {
  __shared__ u16 sm[5120];
  u16* As = sm;
  u16* Bs = sm + 2560;
  int b = blockIdx.z, bm = blockIdx.y, bn = blockIdx.x;
  int t = threadIdx.x, w = t >> 6, lane = t & 63, lr = lane & 15, lg = lane >> 4;
  int wm = w >> 1, wn = w & 1;
  int srow = t >> 2, sch = (t & 3) * 8;
  const u16* Ap = Aw + (size_t)(bm * 64 + srow) * CC + sch;
  const u16* Bp = att + ((size_t)b * NN + bn * 64 + srow) * CC + sch;
  f32x4 acc[2][2] = {};
  for (int kt = 0; kt < CC / 32; ++kt) {
    *(uint4*)&As[srow * 40 + sch] = *(const uint4*)(Ap + kt * 32);
    *(uint4*)&Bs[srow * 40 + sch] = *(const uint4*)(Bp + kt * 32);
    __syncthreads();
    s16x8 af[2], bf[2];
#pragma unroll
    for (int fm = 0; fm < 2; ++fm) af[fm] = *(const s16x8*)&As[(wm * 32 + fm * 16 + lr) * 40 + lg * 8];
#pragma unroll
    for (int fn = 0; fn < 2; ++fn) bf[fn] = *(const s16x8*)&Bs[(wn * 32 + fn * 16 + lr) * 40 + lg * 8];
#pragma unroll
    for (int fm = 0; fm < 2; ++fm)
#pragma unroll
      for (int fn = 0; fn < 2; ++fn)
        acc[fm][fn] = __builtin_amdgcn_mfma_f32_16x16x32_bf16(af[fm], bf[fn], acc[fm][fn], 0, 0, 0);
    __syncthreads();
  }
#pragma unroll
  for (int fm = 0; fm < 2; ++fm)
#pragma unroll
    for (int fn = 0; fn < 2; ++fn)
#pragma unroll
      for (int r = 0; r < 4; ++r) {
        int o = bm * 64 + wm * 32 + fm * 16 + lg * 4 + r;
        int n = bn * 64 + wn * 32 + fn * 16 + lr;
        size_t idx = ((size_t)b * CC + o) * NN + n;
        out[idx] = x[idx] + bias[o] + acc[fm][fn][r];
      }
}

// ---------------- launch ------------------------------------------------
extern "C" void kernel_launch(void* const* d_in, const int* in_sizes, int n_in,
                              void* d_out, int out_size, void* d_ws, size_t ws_size,
                              hipStream_t stream) {
  const float* x  = (const float*)d_in[0];
  const float* nw = (const float*)d_in[1];
  const float* nb = (const float*)d_in[2];
  const float* qw = (const float*)d_in[3];
  const float* qb = (const float*)d_in[4];
  const float* pw = (const float*)d_in[5];
  const float* pb = (const float*)d_in[6];
  float* out = (float*)d_out;
  char* ws = (char*)d_ws;
  float* stats = (float*)(ws + 0);            // 64 f32
  u16* qwb = (u16*)(ws + 4096);               // 768*256 bf16
  u16* pwb = (u16*)(ws + 397312);             // 256*256 bf16
  u16* ht  = (u16*)(ws + 528384);             // [B][N][C] bf16  (8 MB)
  u16* Qt  = (u16*)(ws + 8916992);            // [B][H][N][D] bf16
  u16* Kt  = (u16*)(ws + 17305600);           // [B][H][N][D] bf16
  u16* Vv  = (u16*)(ws + 25694208);           // [B][H][D][N] bf16
  u16* att = (u16*)(ws + 34082816);           // [B][N][C] bf16

  k_prep<<<dim3(256), dim3(256), 0, stream>>>(qw, pw, qwb, pwb, stats);
  k_gn_stats<<<dim3(512), dim3(256), 0, stream>>>(x, stats);
  k_gn_norm<<<dim3(64, 4, NB), dim3(256), 0, stream>>>(x, stats, nw, nb, ht);
  k_qkv<<<dim3(64, 12, NB), dim3(256), 0, stream>>>(qwb, qb, ht, Qt, Kt, Vv);
  k_attn<<<dim3(64, NB * NHEAD), dim3(256), 0, stream>>>(Qt, Kt, Vv, att);
  k_proj<<<dim3(64, 4, NB), dim3(256), 0, stream>>>(pwb, pb, att, x, out);
}

// Round 5
// 175.782 us; speedup vs baseline: 1.6036x; 1.0113x over previous
//
#include <hip/hip_runtime.h>
#include <stdint.h>

// Problem constants: B=4, C=256, H=W=64 -> N=4096, HEADS=4, DH=64, GROUPS=8
#define NB    4
#define CC    256
#define NN    4096
#define NHEAD 4
#define DH    64
#define NGRP  8
#define GSIZE 131072   // (CC/NGRP)*NN elements per (b,group)

typedef unsigned short u16;
typedef __attribute__((ext_vector_type(8))) short s16x8;   // 8 bf16 in 4 VGPRs
typedef __attribute__((ext_vector_type(4))) float f32x4;

__device__ __forceinline__ u16 f2b(float f) {
  uint32_t x = __float_as_uint(f);
  x += 0x7fffu + ((x >> 16) & 1u);   // RNE
  return (u16)(x >> 16);
}

__device__ __forceinline__ uint32_t pk2(float a, float b) {
  uint32_t r;
  asm("v_cvt_pk_bf16_f32 %0, %1, %2" : "=v"(r) : "v"(a), "v"(b));
  return r;   // a -> [15:0], b -> [31:16]
}

// ---------------- prep: zero stats + fp32->bf16 weights ----------------
__global__ __launch_bounds__(256) void k_prep(const float* __restrict__ qw,
                                              const float* __restrict__ pw,
                                              u16* __restrict__ qwb,
                                              u16* __restrict__ pwb,
                                              float* __restrict__ stats) {
  int i = blockIdx.x * 256 + threadIdx.x;
  if (i < 64) stats[i] = 0.f;
  for (int idx = i; idx < 3 * CC * CC; idx += 65536) qwb[idx] = f2b(qw[idx]);
  if (i < CC * CC) pwb[i] = f2b(pw[i]);
}

// ---------------- groupnorm stats: sum/sumsq per (b,g) -----------------
__global__ __launch_bounds__(256) void k_gn_stats(const float* __restrict__ x,
                                                  float* __restrict__ stats) {
  int grp = blockIdx.x >> 4, sub = blockIdx.x & 15;
  const float4* p4 = (const float4*)(x + (size_t)grp * GSIZE + (size_t)sub * 8192);
  float s = 0.f, s2 = 0.f;
#pragma unroll
  for (int i = 0; i < 8; ++i) {
    float4 v = p4[threadIdx.x + 256 * i];
    s  += v.x + v.y + v.z + v.w;
    s2 += v.x * v.x + v.y * v.y + v.z * v.z + v.w * v.w;
  }
#pragma unroll
  for (int off = 1; off < 64; off <<= 1) { s += __shfl_xor(s, off); s2 += __shfl_xor(s2, off); }
  __shared__ float red[8];
  int w = threadIdx.x >> 6;
  if ((threadIdx.x & 63) == 0) { red[w] = s; red[4 + w] = s2; }
  __syncthreads();
  if (threadIdx.x == 0) {
    s  = red[0] + red[1] + red[2] + red[3];
    s2 = red[4] + red[5] + red[6] + red[7];
    atomicAdd(&stats[grp], s);
    atomicAdd(&stats[32 + grp], s2);
  }
}

// ------------- groupnorm normalize + transpose to h_t[b][n][c] ---------
__global__ __launch_bounds__(256) void k_gn_norm(const float* __restrict__ x,
                                                 const float* __restrict__ stats,
                                                 const float* __restrict__ gw,
                                                 const float* __restrict__ gb,
                                                 u16* __restrict__ ht) {
  __shared__ u16 T[64 * 72];
  int b = blockIdx.z, cb = blockIdx.y, nb = blockIdx.x;
  int t = threadIdx.x;
  int c = t >> 2, nch = (t & 3) * 16;
  int cg = cb * 64 + c;
  int grp = b * NGRP + (cg >> 5);
  float mean = stats[grp] * (1.f / (float)GSIZE);
  float var  = stats[32 + grp] * (1.f / (float)GSIZE) - mean * mean;
  float rstd = rsqrtf(var + 1e-5f);
  float ga = gw[cg] * rstd;
  float be = gb[cg] - mean * ga;
  const float* px = x + ((size_t)b * CC + cg) * NN + nb * 64 + nch;
#pragma unroll
  for (int k = 0; k < 4; ++k) {
    float4 v = *(const float4*)(px + 4 * k);
    int nl = nch + 4 * k;
    T[(nl + 0) * 72 + c] = f2b(v.x * ga + be);
    T[(nl + 1) * 72 + c] = f2b(v.y * ga + be);
    T[(nl + 2) * 72 + c] = f2b(v.z * ga + be);
    T[(nl + 3) * 72 + c] = f2b(v.w * ga + be);
  }
  __syncthreads();
  int n = t >> 2, cch = (t & 3) * 16;
  u16* dst = ht + ((size_t)b * NN + nb * 64 + n) * CC + cb * 64 + cch;
  *(uint4*)(dst)     = *(const uint4*)&T[n * 72 + cch];
  *(uint4*)(dst + 8) = *(const uint4*)&T[n * 72 + cch + 8];
}

// ---------------- QKV GEMM: C[o][n] = qkv_w[o][:] . h[:, n] ------------
__global__ __launch_bounds__(256) void k_qkv(const u16* __restrict__ Aw,
                                             const float* __restrict__ bias,
                                             const u16* __restrict__ ht,
                                             u16* __restrict__ Qt,
                                             u16* __restrict__ Kt,
                                             u16* __restrict__ Vv) {
  __shared__ u16 sm[5120];            // As[64][40] | Bs[64][40]; reused as Ts[64][72]
  u16* As = sm;
  u16* Bs = sm + 2560;
  int b = blockIdx.z, bm = blockIdx.y, bn = blockIdx.x;
  int t = threadIdx.x, w = t >> 6, lane = t & 63, lr = lane & 15, lg = lane >> 4;
  int wm = w >> 1, wn = w & 1;
  int srow = t >> 2, sch = (t & 3) * 8;
  const u16* Ap = Aw + (size_t)(bm * 64 + srow) * CC + sch;
  const u16* Bp = ht + ((size_t)b * NN + bn * 64 + srow) * CC + sch;
  f32x4 acc[2][2] = {};
  for (int kt = 0; kt < CC / 32; ++kt) {
    *(uint4*)&As[srow * 40 + sch] = *(const uint4*)(Ap + kt * 32);
    *(uint4*)&Bs[srow * 40 + sch] = *(const uint4*)(Bp + kt * 32);
    __syncthreads();
    s16x8 af[2], bf[2];
#pragma unroll
    for (int fm = 0; fm < 2; ++fm) af[fm] = *(const s16x8*)&As[(wm * 32 + fm * 16 + lr) * 40 + lg * 8];
#pragma unroll
    for (int fn = 0; fn < 2; ++fn) bf[fn] = *(const s16x8*)&Bs[(wn * 32 + fn * 16 + lr) * 40 + lg * 8];
#pragma unroll
    for (int fm = 0; fm < 2; ++fm)
#pragma unroll
      for (int fn = 0; fn < 2; ++fn)
        acc[fm][fn] = __builtin_amdgcn_mfma_f32_16x16x32_bf16(af[fm], bf[fn], acc[fm][fn], 0, 0, 0);
    __syncthreads();
  }
  int which = bm >> 2, head = bm & 3;
  if (which == 2) {           // V[b][h][d][n], d = local row m
#pragma unroll
    for (int fm = 0; fm < 2; ++fm)
#pragma unroll
      for (int fn = 0; fn < 2; ++fn)
#pragma unroll
        for (int r = 0; r < 4; ++r) {
          int m = wm * 32 + fm * 16 + lg * 4 + r;
          int n = wn * 32 + fn * 16 + lr;
          float v = acc[fm][fn][r] + bias[bm * 64 + m];
          Vv[((size_t)(b * NHEAD + head) * DH + m) * NN + bn * 64 + n] = f2b(v);
        }
  } else {                    // Qt/Kt[b][h][n][d] via LDS transpose
    u16* Ts = sm;             // [64 n][72]
    // Q carries 1/sqrt(d) * log2(e) so attention scores are in exp2 domain
    float scale = (which == 0) ? 0.125f * 1.44269504f : 1.0f;
#pragma unroll
    for (int fm = 0; fm < 2; ++fm)
#pragma unroll
      for (int fn = 0; fn < 2; ++fn)
#pragma unroll
        for (int r = 0; r < 4; ++r) {
          int m = wm * 32 + fm * 16 + lg * 4 + r;
          int n = wn * 32 + fn * 16 + lr;
          float v = (acc[fm][fn][r] + bias[bm * 64 + m]) * scale;
          Ts[n * 72 + m] = f2b(v);
        }
    __syncthreads();
    u16* dst = (which == 0 ? Qt : Kt);
    int n = t >> 2, cch = (t & 3) * 16;
    u16* o = dst + ((size_t)(b * NHEAD + head) * NN + bn * 64 + n) * DH + cch;
    *(uint4*)(o)     = *(const uint4*)&Ts[n * 72 + cch];
    *(uint4*)(o + 8) = *(const uint4*)&Ts[n * 72 + cch + 8];
  }
}

// ---------------- flash attention (KVBLK=128, MFMA row-sum) ------------
// grid (qtile=N/64, b*h). 4 waves x 16 q-rows. S^T = K.Q^T (swapped ops):
// lane owns q-row i=lane&15; K rows staged pi-permuted per 64-sub-tile so
// the S^T accumulator IS the PV B-frag layout (repack = 16 cvt_pk, no LDS).
// Row-sum l comes from an extra MFMA with A=ones (no v_add / shfl chain).
__global__ __launch_bounds__(256, 4) void k_attn(const u16* __restrict__ Qt,
                                                 const u16* __restrict__ Kt,
                                                 const u16* __restrict__ Vv,
                                                 u16* __restrict__ att) {
  __shared__ __align__(16) u16 Ks[128 * 72];   // [rho][d]  18432 B
  __shared__ __align__(16) u16 Vs[64 * 136];   // [d][j]    17408 B
  int bh = blockIdx.y, qt = blockIdx.x;
  int t = threadIdx.x, w = t >> 6, lane = t & 63, lr = lane & 15, lg = lane >> 4;
  const u16* Qb = Qt + ((size_t)bh * NN + qt * 64 + w * 16) * DH;
  const u16* Kb = Kt + (size_t)bh * NN * DH;
  const u16* Vb = Vv + (size_t)bh * DH * NN;
  // Q B-frag: B[k=d][col=i=lr]
  s16x8 bq[2];
#pragma unroll
  for (int kk = 0; kk < 2; ++kk) bq[kk] = *(const s16x8*)(Qb + lr * DH + kk * 32 + lg * 8);
  const s16x8 ones = (s16x8)(short)0x3F80;   // bf16 1.0 splat (A-frag of ones)
  float m = -1e30f;
  f32x4 oacc[4] = {};
  f32x4 lacc = {};
  // K staging: thread covers LDS row srK (0..127), 32 u16 at scK.
  // pi within each 64 sub-tile: rho[jt1 jt0 lg1 lg0 r1 r0] -> j[jt1 lg1 lg0 jt0 r1 r0]
  int srK = t >> 1, scK = (t & 1) * 32;
  int wK = srK & 63;
  int prK = (srK & 64) | (wK & 32) | (((wK >> 2) & 3) << 3) | (((wK >> 4) & 1) << 2) | (wK & 3);
  const u16* kp0 = Kb + (size_t)prK * DH + scK;
  u16* ksw = &Ks[srK * 72 + scK];
  // V staging: natural [d][j]; thread covers row srV, 32 u16 at scV
  int srV = t >> 2, scV = (t & 3) * 32;
  const u16* vp0 = Vb + (size_t)srV * NN + scV;
  u16* vsw = &Vs[srV * 136 + scV];
  // prologue: stage tile 0
  {
    uint4 a0 = *(const uint4*)(kp0),      a1 = *(const uint4*)(kp0 + 8);
    uint4 a2 = *(const uint4*)(kp0 + 16), a3 = *(const uint4*)(kp0 + 24);
    uint4 b0 = *(const uint4*)(vp0),      b1 = *(const uint4*)(vp0 + 8);
    uint4 b2 = *(const uint4*)(vp0 + 16), b3 = *(const uint4*)(vp0 + 24);
    *(uint4*)(ksw) = a0; *(uint4*)(ksw + 8) = a1; *(uint4*)(ksw + 16) = a2; *(uint4*)(ksw + 24) = a3;
    *(uint4*)(vsw) = b0; *(uint4*)(vsw + 8) = b1; *(uint4*)(vsw + 16) = b2; *(uint4*)(vsw + 24) = b3;
  }
  __syncthreads();
  for (int j0 = 0; j0 < NN; j0 += 128) {
    // prefetch next tile into regs (held across the body)
    int jn = (j0 + 128 < NN) ? j0 + 128 : 0;
    const u16* kp = kp0 + (size_t)jn * DH;
    const u16* vp = vp0 + jn;
    uint4 rka = *(const uint4*)(kp),      rkb = *(const uint4*)(kp + 8);
    uint4 rkc = *(const uint4*)(kp + 16), rkd = *(const uint4*)(kp + 24);
    uint4 rva = *(const uint4*)(vp),      rvb = *(const uint4*)(vp + 8);
    uint4 rvc = *(const uint4*)(vp + 16), rvd = *(const uint4*)(vp + 24);
    // S^T: 8 sub-blocks of 16 staged rows, K=64 in 2 chunks
    f32x4 s[8];
    __builtin_amdgcn_s_setprio(1);
#pragma unroll
    for (int q = 0; q < 8; ++q) {
      const u16* base = &Ks[(q * 16 + lr) * 72 + lg * 8];
      s16x8 a0 = *(const s16x8*)(base);
      s16x8 a1 = *(const s16x8*)(base + 32);
      f32x4 z = {};
      z = __builtin_amdgcn_mfma_f32_16x16x32_bf16(a0, bq[0], z, 0, 0, 0);
      z = __builtin_amdgcn_mfma_f32_16x16x32_bf16(a1, bq[1], z, 0, 0, 0);
      s[q] = z;
    }
    __builtin_amdgcn_s_setprio(0);
    // row max over 32 values (fmax triples -> v_max3) + 2 shfl
    float mx = fmaxf(s[0][0], s[0][1]);
    mx = fmaxf(mx, fmaxf(s[0][2], s[0][3]));
#pragma unroll
    for (int q = 1; q < 8; ++q) {
      mx = fmaxf(mx, fmaxf(s[q][0], s[q][1]));
      mx = fmaxf(mx, fmaxf(s[q][2], s[q][3]));
    }
    mx = fmaxf(mx, __shfl_xor(mx, 16));
    mx = fmaxf(mx, __shfl_xor(mx, 32));
    // defer-max: rescale only if some row grew by > 8 (exp2 domain)
    if (__any(mx > m + 8.f)) {
      float mnew  = fmaxf(m, mx);
      float alpha = exp2f(m - mnew);
#pragma unroll
      for (int dt = 0; dt < 4; ++dt)
#pragma unroll
        for (int r = 0; r < 4; ++r) oacc[dt][r] *= alpha;
#pragma unroll
      for (int r = 0; r < 4; ++r) lacc[r] *= alpha;
      m = mnew;
    }
    // exp2 + pack into PV B-frags: chunk c = (q>>2)*2 + ((q>>1)&1), idx = (q&1)*4 + r
    union { s16x8 v; uint32_t u[4]; } pb[4];
#pragma unroll
    for (int q = 0; q < 8; ++q) {
      float p0 = exp2f(s[q][0] - m);
      float p1 = exp2f(s[q][1] - m);
      float p2 = exp2f(s[q][2] - m);
      float p3 = exp2f(s[q][3] - m);
      int c = (q >> 2) * 2 + ((q >> 1) & 1);
      pb[c].u[(q & 1) * 2]     = pk2(p0, p1);
      pb[c].u[(q & 1) * 2 + 1] = pk2(p2, p3);
    }
    // O^T += V^T.P^T ; l += ones.P^T (row-sum via matrix pipe)
    __builtin_amdgcn_s_setprio(1);
#pragma unroll
    for (int dt = 0; dt < 4; ++dt) {
      const u16* vb2 = &Vs[(dt * 16 + lr) * 136 + lg * 8];
#pragma unroll
      for (int c = 0; c < 4; ++c) {
        s16x8 av = *(const s16x8*)(vb2 + c * 32);
        oacc[dt] = __builtin_amdgcn_mfma_f32_16x16x32_bf16(av, pb[c].v, oacc[dt], 0, 0, 0);
      }
    }
#pragma unroll
    for (int c = 0; c < 4; ++c)
      lacc = __builtin_amdgcn_mfma_f32_16x16x32_bf16(ones, pb[c].v, lacc, 0, 0, 0);
    __builtin_amdgcn_s_setprio(0);
    __syncthreads();   // all waves done reading Ks/Vs
    *(uint4*)(ksw) = rka; *(uint4*)(ksw + 8) = rkb; *(uint4*)(ksw + 16) = rkc; *(uint4*)(ksw + 24) = rkd;
    *(uint4*)(vsw) = rva; *(uint4*)(vsw + 8) = rvb; *(uint4*)(vsw + 16) = rvc; *(uint4*)(vsw + 24) = rvd;
    __syncthreads();   // next tile staged
  }
  // write att[b][n][c]: n = qt*64+w*16+lr, c = h*64 + dt*16 + lg*4 + r
  float linv = 1.f / lacc[0];
  int b = bh >> 2, h = bh & 3;
  u16* ob = att + ((size_t)b * NN + qt * 64 + w * 16 + lr) * CC + h * 64 + lg * 4;
#pragma unroll
  for (int dt = 0; dt < 4; ++dt) {
    uint2 pkd;
    pkd.x = pk2(oacc[dt][0] * linv, oacc[dt][1] * linv);
    pkd.y = pk2(oacc[dt][2] * linv, oacc[dt][3] * linv);
    *(uint2*)(ob + dt * 16) = pkd;
  }
}

// ---------------- proj GEMM + residual ---------------------------------
__global__ __launch_bounds__(256) void k_proj(const u16* __restrict__ Aw,
                                              const float* __restrict__ bias,
                                              const u16* __restrict__ att,
                                              const float* __restrict__ x,
                                              float* __restrict__ out) {
  __shared__ u16 sm[5120];
  u16* As = sm;
  u16* Bs = sm + 2560;
  int b = blockIdx.z, bm = blockIdx.y, bn = blockIdx.x;
  int t = threadIdx.x, w = t >> 6, lane = t & 63, lr = lane & 15, lg = lane >> 4;
  int wm = w >> 1, wn = w & 1;
  int srow = t >> 2, sch = (t & 3) * 8;
  const u16* Ap = Aw + (size_t)(bm * 64 + srow) * CC + sch;
  const u16* Bp = att + ((size_t)b * NN + bn * 64 + srow) * CC + sch;
  f32x4 acc[2][2] = {};
  for (int kt = 0; kt < CC / 32; ++kt) {
    *(uint4*)&As[srow * 40 + sch] = *(const uint4*)(Ap + kt * 32);
    *(uint4*)&Bs[srow * 40 + sch] = *(const uint4*)(Bp + kt * 32);
    __syncthreads();
    s16x8 af[2], bf[2];
#pragma unroll
    for (int fm = 0; fm < 2; ++fm) af[fm] = *(const s16x8*)&As[(wm * 32 + fm * 16 + lr) * 40 + lg * 8];
#pragma unroll
    for (int fn = 0; fn < 2; ++fn) bf[fn] = *(const s16x8*)&Bs[(wn * 32 + fn * 16 + lr) * 40 + lg * 8];
#pragma unroll
    for (int fm = 0; fm < 2; ++fm)
#pragma unroll
      for (int fn = 0; fn < 2; ++fn)
        acc[fm][fn] = __builtin_amdgcn_mfma_f32_16x16x32_bf16(af[fm], bf[fn], acc[fm][fn], 0, 0, 0);
    __syncthreads();
  }
#pragma unroll
  for (int fm = 0; fm < 2; ++fm)
#pragma unroll
    for (int fn = 0; fn < 2; ++fn)
#pragma unroll
      for (int r = 0; r < 4; ++r) {
        int o = bm * 64 + wm * 32 + fm * 16 + lg * 4 + r;
        int n = bn * 64 + wn * 32 + fn * 16 + lr;
        size_t idx = ((size_t)b * CC + o) * NN + n;
        out[idx] = x[idx] + bias[o] + acc[fm][fn][r];
      }
}

// ---------------- launch ------------------------------------------------
extern "C" void kernel_launch(void* const* d_in, const int* in_sizes, int n_in,
                              void* d_out, int out_size, void* d_ws, size_t ws_size,
                              hipStream_t stream) {
  const float* x  = (const float*)d_in[0];
  const float* nw = (const float*)d_in[1];
  const float* nb = (const float*)d_in[2];
  const float* qw = (const float*)d_in[3];
  const float* qb = (const float*)d_in[4];
  const float* pw = (const float*)d_in[5];
  const float* pb = (const float*)d_in[6];
  float* out = (float*)d_out;
  char* ws = (char*)d_ws;
  float* stats = (float*)(ws + 0);            // 64 f32
  u16* qwb = (u16*)(ws + 4096);               // 768*256 bf16
  u16* pwb = (u16*)(ws + 397312);             // 256*256 bf16
  u16* ht  = (u16*)(ws + 528384);             // [B][N][C] bf16  (8 MB)
  u16* Qt  = (u16*)(ws + 8916992);            // [B][H][N][D] bf16
  u16* Kt  = (u16*)(ws + 17305600);           // [B][H][N][D] bf16
  u16* Vv  = (u16*)(ws + 25694208);           // [B][H][D][N] bf16
  u16* att = (u16*)(ws + 34082816);           // [B][N][C] bf16

  k_prep<<<dim3(256), dim3(256), 0, stream>>>(qw, pw, qwb, pwb, stats);
  k_gn_stats<<<dim3(512), dim3(256), 0, stream>>>(x, stats);
  k_gn_norm<<<dim3(64, 4, NB), dim3(256), 0, stream>>>(x, stats, nw, nb, ht);
  k_qkv<<<dim3(64, 12, NB), dim3(256), 0, stream>>>(qwb, qb, ht, Qt, Kt, Vv);
  k_attn<<<dim3(64, NB * NHEAD), dim3(256), 0, stream>>>(Qt, Kt, Vv, att);
  k_proj<<<dim3(64, 4, NB), dim3(256), 0, stream>>>(pwb, pb, att, x, out);
}